// Round 1
// baseline (155.801 us; speedup 1.0000x reference)
//
#include <hip/hip_runtime.h>
#include <math.h>

// S4 diagonal SSM: B=2, L=2048, H=512, N=64.
// Chunked formulation: T=64, NC=32.
//   y[cT+t'] = D*u + sum_{tau<=t'} K[h,tau]*u[t-tau] + sum_n Cpow[t',n,h]*S_c[b,n,h]
//   K[h,tau]     = sum_n C[n]*B_d[h,n]*A_d[h,n]^tau
//   Cpow[t',n,h] = C[n]*A_d[h,n]^(t'+1)
//   S_c = A_d^T * S_{c-1} + xlocal[c-1],  xlocal[c] = sum_{s'} A_d^{T-1-s'} B_d u[cT+s']

#define BATCH   2
#define SEQLEN  2048
#define DMODEL  512
#define DSTATE  64
#define T_CHUNK 64
#define NCHUNK  (SEQLEN / T_CHUNK)   // 32

__device__ __forceinline__ float A_cont(int n) {
    // A[n] = exp(-0.5*log1p((n+1)/64)) = (1 + (n+1)/64)^(-1/2)
    return rsqrtf(1.0f + (float)(n + 1) * (1.0f / 64.0f));
}

// ---------------- Kernel 1a: K_T[tau][h]  (512 waves, lane = n) ----------------
__global__ __launch_bounds__(256) void k_kernelK(const float* __restrict__ B_re,
                                                 const float* __restrict__ C_re,
                                                 const float* __restrict__ log_dt,
                                                 float* __restrict__ K_T) {
    int g = blockIdx.x * blockDim.x + threadIdx.x;   // 32768 threads = 512 waves
    int lane = g & 63;      // n
    int h = g >> 6;
    float delta = expf(log_dt[h]);
    float dA = delta * A_cont(lane);
    float Ad = expf(dA);
    float Bd = expm1f(dA) * B_re[lane] * delta;
    float v = C_re[lane] * Bd;
    float p = 1.0f;
    for (int tau = 0; tau < T_CHUNK; ++tau) {
        float contrib = v * p;
        #pragma unroll
        for (int m = 32; m > 0; m >>= 1) contrib += __shfl_xor(contrib, m, 64);
        if (lane == 0) K_T[tau * DMODEL + h] = contrib;
        p *= Ad;
    }
}

// ---------------- Kernel 1b: Cpow[t'][n][h] ----------------
__global__ __launch_bounds__(256) void k_cpow(const float* __restrict__ C_re,
                                              const float* __restrict__ log_dt,
                                              float* __restrict__ Cpow) {
    int g = blockIdx.x * blockDim.x + threadIdx.x;   // 32768 threads: h fastest
    int h = g & (DMODEL - 1);
    int n = g >> 9;                                  // 0..63
    float delta = expf(log_dt[h]);
    float Ad = expf(delta * A_cont(n));
    float p = C_re[n] * Ad;                          // C*A_d^1
    for (int tp = 0; tp < T_CHUNK; ++tp) {
        Cpow[(tp * DSTATE + n) * DMODEL + h] = p;    // coalesced in h
        p *= Ad;
    }
}

// ---------------- Kernel 2: xlocal[b][c][n][h] (lane = h, 8 states/lane) ----------------
__global__ __launch_bounds__(256) void k_xlocal(const float* __restrict__ u,
                                                const float* __restrict__ B_re,
                                                const float* __restrict__ log_dt,
                                                float* __restrict__ xl) {
    int g = blockIdx.x * blockDim.x + threadIdx.x;   // 262144 threads = 4096 waves
    int lane = g & 63;
    int w = g >> 6;
    int hb = w & 7;              // h block (8 x 64)
    int ng = (w >> 3) & 7;       // n group (8 x 8)
    int c  = (w >> 6) & (NCHUNK - 1);
    int b  = w >> 11;
    int h = hb * 64 + lane;
    float delta = expf(log_dt[h]);
    float Ad[8], Bd[8], x[8];
    #pragma unroll
    for (int nn = 0; nn < 8; ++nn) {
        int n = ng * 8 + nn;
        float dA = delta * A_cont(n);
        Ad[nn] = expf(dA);
        Bd[nn] = expm1f(dA) * B_re[n] * delta;
        x[nn] = 0.0f;
    }
    const float* up = u + ((size_t)(b * SEQLEN + c * T_CHUNK)) * DMODEL + h;
    #pragma unroll 4
    for (int s = 0; s < T_CHUNK; ++s) {
        float uv = up[s * DMODEL];                   // coalesced in h
        #pragma unroll
        for (int nn = 0; nn < 8; ++nn)
            x[nn] = fmaf(Ad[nn], x[nn], Bd[nn] * uv);
    }
    float* xp = xl + ((size_t)((b * NCHUNK + c) * DSTATE + ng * 8)) * DMODEL + h;
    #pragma unroll
    for (int nn = 0; nn < 8; ++nn) xp[nn * DMODEL] = x[nn];
}

// ---------------- Kernel 3: in-place chunk-state scan ----------------
// After this, xl[b][c-1][n][h] holds S_c (state entering chunk c), for c = 1..NC-1.
__global__ __launch_bounds__(256) void k_scan(const float* __restrict__ log_dt,
                                              float* __restrict__ xl) {
    int g = blockIdx.x * blockDim.x + threadIdx.x;   // 65536 threads, h fastest
    int h = g & (DMODEL - 1);
    int n = (g >> 9) & (DSTATE - 1);
    int b = g >> 15;
    float delta = expf(log_dt[h]);
    float ApT = expf(delta * A_cont(n) * (float)T_CHUNK);   // A_d^T
    float s = 0.0f;
    float* base = xl + ((size_t)(b * NCHUNK * DSTATE + n)) * DMODEL + h;
    for (int cm1 = 0; cm1 < NCHUNK - 1; ++cm1) {
        float v = base[(size_t)cm1 * DSTATE * DMODEL];
        s = fmaf(ApT, s, v);                          // S_{cm1+1}
        base[(size_t)cm1 * DSTATE * DMODEL] = s;
    }
}

// ---------------- Kernel 4: output ----------------
__global__ __launch_bounds__(256) void k_out(const float* __restrict__ u,
                                             const float* __restrict__ D,
                                             const float* __restrict__ K_T,
                                             const float* __restrict__ Cpow,
                                             const float* __restrict__ Sbuf,
                                             float* __restrict__ out) {
    int g = blockIdx.x * blockDim.x + threadIdx.x;   // 2M threads, h fastest
    int h = g & (DMODEL - 1);
    int t = (g >> 9) & (SEQLEN - 1);
    int b = g >> 20;
    int c = t >> 6;
    int tp = t & 63;                                  // wave-uniform
    float yv = D[h] * u[g];
    const float* ub = u + g;
    #pragma unroll 4
    for (int tau = 0; tau <= tp; ++tau)               // intra-chunk causal conv
        yv = fmaf(K_T[tau * DMODEL + h], ub[-(tau * DMODEL)], yv);
    if (c > 0) {                                      // chunk-start-state correction
        const float* sp = Sbuf + ((size_t)((b * NCHUNK + (c - 1)) * DSTATE)) * DMODEL + h;
        const float* cp = Cpow + ((size_t)(tp * DSTATE)) * DMODEL + h;
        #pragma unroll 8
        for (int n = 0; n < DSTATE; ++n)
            yv = fmaf(cp[n * DMODEL], sp[n * DMODEL], yv);
    }
    out[g] = yv;
}

extern "C" void kernel_launch(void* const* d_in, const int* in_sizes, int n_in,
                              void* d_out, int out_size, void* d_ws, size_t ws_size,
                              hipStream_t stream) {
    const float* u      = (const float*)d_in[0];
    const float* B_re   = (const float*)d_in[1];
    const float* C_re   = (const float*)d_in[2];
    const float* log_dt = (const float*)d_in[3];
    const float* D      = (const float*)d_in[4];
    float* out = (float*)d_out;
    float* ws  = (float*)d_ws;

    // Workspace layout (floats): Cpow [64*64*512]=2097152 | K_T [64*512]=32768 | xl [2*32*64*512]=2097152
    float* Cpow = ws;
    float* K_T  = ws + 2097152;
    float* xl   = ws + 2097152 + 32768;

    k_kernelK<<<128, 256, 0, stream>>>(B_re, C_re, log_dt, K_T);
    k_cpow  <<<128, 256, 0, stream>>>(C_re, log_dt, Cpow);
    k_xlocal<<<1024, 256, 0, stream>>>(u, B_re, log_dt, xl);
    k_scan  <<<256, 256, 0, stream>>>(log_dt, xl);
    k_out   <<<8192, 256, 0, stream>>>(u, D, K_T, Cpow, xl, out);
}

// Round 2
// 109.728 us; speedup vs baseline: 1.4199x; 1.4199x over previous
//
#include <hip/hip_runtime.h>
#include <math.h>

// S4 diagonal SSM: B=2, L=2048, H=512, N=64. Chunked: T=64, NC=32.
// y[cT+t'] = sum_{tau<=t'} Kd[h,tau]*u[t-tau] + sum_n C[n]*A_d^(t'+1)*S_c[b,n,h]
//   (D folded into Kd[0]); S_c propagated by chunk scan over local end-states.

#define BATCH   2
#define SEQLEN  2048
#define DMODEL  512
#define DSTATE  64
#define T_CHUNK 64
#define NCHUNK  (SEQLEN / T_CHUNK)   // 32
#define RT      8                    // outputs per thread in k_out

__device__ __forceinline__ float A_cont(int n) {
    // A[n] = (1 + (n+1)/64)^(-1/2)
    return rsqrtf(1.0f + (float)(n + 1) * (1.0f / 64.0f));
}

// ---------------- Kernel 1: fused setup (Kbuf, AdTab, CpowStep) ----------------
// 32768 threads: thread (j,h), j=0..63, h fastest.
//   Kbuf[72][512]: rows 0..7 zero, row 8+tau = K[tau][h] (+D[h] at tau=0)
//   AdTab[n][h]   = exp(delta*A[n])
//   CpowStep[i][n][h] = C[n]*Ad^(8i+1)   (i = t'-tile index)
__global__ __launch_bounds__(256) void k_setup(const float* __restrict__ B_re,
                                               const float* __restrict__ C_re,
                                               const float* __restrict__ log_dt,
                                               const float* __restrict__ D,
                                               float* __restrict__ Kbuf,
                                               float* __restrict__ AdTab,
                                               float* __restrict__ CpowStep) {
    int g = blockIdx.x * blockDim.x + threadIdx.x;
    int h = g & (DMODEL - 1);
    int j = g >> 9;                       // 0..63
    float delta = expf(log_dt[h]);
    float dAj = delta * A_cont(j);
    float Adj = expf(dAj);
    AdTab[j * DMODEL + h] = Adj;
    float e8 = Adj * Adj; e8 = e8 * e8; e8 = e8 * e8;   // Adj^8
    float p = C_re[j] * Adj;                            // C*Ad^1
    #pragma unroll
    for (int i = 0; i < RT; ++i) {
        CpowStep[(i * DSTATE + j) * DMODEL + h] = p;
        p *= e8;
    }
    // K row tau=j: sum_n C[n]*Bd[n,h]*Ad[n,h]^j
    float acc = (j == 0) ? D[h] : 0.0f;
    for (int n = 0; n < DSTATE; ++n) {
        float dAn = delta * A_cont(n);
        float Bd = expm1f(dAn) * B_re[n] * delta;
        acc = fmaf(C_re[n] * Bd, expf(dAn * (float)j), acc);
    }
    Kbuf[(8 + j) * DMODEL + h] = acc;
    if (j < 8) Kbuf[j * DMODEL + h] = 0.0f;   // zero-pad rows for branch-free conv
}

// ---------------- Kernel 2: xlocal[b][c][n][h] (lane = h, 8 states/lane) ----------------
__global__ __launch_bounds__(256) void k_xlocal(const float* __restrict__ u,
                                                const float* __restrict__ B_re,
                                                const float* __restrict__ log_dt,
                                                float* __restrict__ xl) {
    int g = blockIdx.x * blockDim.x + threadIdx.x;   // 262144 threads
    int lane = g & 63;
    int w = g >> 6;
    int hb = w & 7;              // h block (8 x 64)
    int ng = (w >> 3) & 7;       // n group (8 x 8)
    int c  = (w >> 6) & (NCHUNK - 1);
    int b  = w >> 11;
    int h = hb * 64 + lane;
    float delta = expf(log_dt[h]);
    float Ad[8], Bd[8], x[8];
    #pragma unroll
    for (int nn = 0; nn < 8; ++nn) {
        int n = ng * 8 + nn;
        float dA = delta * A_cont(n);
        Ad[nn] = expf(dA);
        Bd[nn] = expm1f(dA) * B_re[n] * delta;
        x[nn] = 0.0f;
    }
    const float* up = u + ((size_t)(b * SEQLEN + c * T_CHUNK)) * DMODEL + h;
    #pragma unroll 4
    for (int s = 0; s < T_CHUNK; ++s) {
        float uv = up[(size_t)s * DMODEL];           // coalesced in h
        #pragma unroll
        for (int nn = 0; nn < 8; ++nn)
            x[nn] = fmaf(Ad[nn], x[nn], Bd[nn] * uv);
    }
    float* xp = xl + ((size_t)((b * NCHUNK + c) * DSTATE + ng * 8)) * DMODEL + h;
    #pragma unroll
    for (int nn = 0; nn < 8; ++nn) xp[(size_t)nn * DMODEL] = x[nn];
}

// ---------------- Kernel 3: in-place chunk-state scan ----------------
// After: xl[b][c-1][n][h] holds S_c (state entering chunk c), c = 1..NC-1.
__global__ __launch_bounds__(256) void k_scan(const float* __restrict__ log_dt,
                                              float* __restrict__ xl) {
    int g = blockIdx.x * blockDim.x + threadIdx.x;   // 65536 threads, h fastest
    int h = g & (DMODEL - 1);
    int n = (g >> 9) & (DSTATE - 1);
    int b = g >> 15;
    float delta = expf(log_dt[h]);
    float ApT = expf(delta * A_cont(n) * (float)T_CHUNK);   // A_d^T
    float s = 0.0f;
    float* base = xl + ((size_t)(b * NCHUNK * DSTATE + n)) * DMODEL + h;
    for (int cm1 = 0; cm1 < NCHUNK - 1; ++cm1) {
        float v = base[(size_t)cm1 * DSTATE * DMODEL];
        s = fmaf(ApT, s, v);
        base[(size_t)cm1 * DSTATE * DMODEL] = s;
    }
}

// ---------------- Kernel 4: output, 8 t' per thread ----------------
__global__ __launch_bounds__(256) void k_out(const float* __restrict__ u,
                                             const float* __restrict__ Kbuf,
                                             const float* __restrict__ AdTab,
                                             const float* __restrict__ CpowStep,
                                             const float* __restrict__ Sbuf,
                                             float* __restrict__ out) {
    int g = blockIdx.x * blockDim.x + threadIdx.x;   // 262144 threads
    int h  = g & (DMODEL - 1);
    int it = (g >> 9) & 7;            // t'-tile (wave-uniform)
    int c  = (g >> 12) & (NCHUNK - 1);
    int b  = g >> 17;
    int tp0 = it * RT;

    const float* ubase = u + ((size_t)(b * SEQLEN + c * T_CHUNK)) * DMODEL + h;
    const float* kb = Kbuf + h;

    float acc[RT], kreg[RT];
    #pragma unroll
    for (int i = 0; i < RT; ++i) {
        acc[i] = 0.0f;
        kreg[i] = kb[(size_t)(8 + tp0 + i) * DMODEL];
    }

    // causal conv: sliding K-window, 1 u load + 1 K load + 8 FMA per step
    for (int s8 = 0; s8 <= it; ++s8) {
        #pragma unroll
        for (int q = 0; q < 8; ++q) {
            int s = s8 * 8 + q;
            float uv = ubase[(size_t)s * DMODEL];
            #pragma unroll
            for (int i = 0; i < RT; ++i) acc[i] = fmaf(kreg[i], uv, acc[i]);
            #pragma unroll
            for (int i = RT - 1; i > 0; --i) kreg[i] = kreg[i - 1];
            kreg[0] = kb[(size_t)(8 + tp0 - s - 1) * DMODEL];   // row 0 (zeros) at the end
        }
    }

    // chunk-entry-state correction: z[i] = sum_n C*Ad^(tp0+i+1) * S[n]
    if (c > 0) {
        const float* sp = Sbuf + ((size_t)((b * NCHUNK + (c - 1)) * DSTATE)) * DMODEL + h;
        const float* ap = AdTab + h;
        const float* cp = CpowStep + (size_t)(it * DSTATE) * DMODEL + h;
        #pragma unroll 4
        for (int n = 0; n < DSTATE; ++n) {
            float Sv  = sp[(size_t)n * DMODEL];
            float Adv = ap[(size_t)n * DMODEL];
            float w   = cp[(size_t)n * DMODEL] * Sv;
            acc[0] += w;
            #pragma unroll
            for (int i = 1; i < RT; ++i) { w *= Adv; acc[i] += w; }
        }
    }

    float* ob = out + ((size_t)(b * SEQLEN + c * T_CHUNK + tp0)) * DMODEL + h;
    #pragma unroll
    for (int i = 0; i < RT; ++i) ob[(size_t)i * DMODEL] = acc[i];
}

extern "C" void kernel_launch(void* const* d_in, const int* in_sizes, int n_in,
                              void* d_out, int out_size, void* d_ws, size_t ws_size,
                              hipStream_t stream) {
    const float* u      = (const float*)d_in[0];
    const float* B_re   = (const float*)d_in[1];
    const float* C_re   = (const float*)d_in[2];
    const float* log_dt = (const float*)d_in[3];
    const float* D      = (const float*)d_in[4];
    float* out = (float*)d_out;
    float* ws  = (float*)d_ws;

    // ws layout (floats):
    float* Kbuf     = ws;                      // 72*512      = 36864
    float* AdTab    = ws + 36864;              // 64*512      = 32768
    float* CpowStep = ws + 36864 + 32768;      // 8*64*512    = 262144
    float* xl       = ws + 36864 + 32768 + 262144;  // 2*32*64*512 = 2097152  (total ~9.7 MB)

    k_setup <<<128, 256, 0, stream>>>(B_re, C_re, log_dt, D, Kbuf, AdTab, CpowStep);
    k_xlocal<<<1024, 256, 0, stream>>>(u, B_re, log_dt, xl);
    k_scan  <<<256, 256, 0, stream>>>(log_dt, xl);
    k_out   <<<1024, 256, 0, stream>>>(u, Kbuf, AdTab, CpowStep, xl, out);
}

// Round 3
// 109.095 us; speedup vs baseline: 1.4281x; 1.0058x over previous
//
#include <hip/hip_runtime.h>
#include <math.h>

// S4 diagonal SSM: B=2, L=2048, H=512, N=64. Chunked: T=64, NC=32.
// y[cT+t'] = sum_{tau<=t'} Kd[h,tau]*u[t-tau] + sum_n C[n]*A_d^(t'+1)*S_c[b,n,h]
//   (D folded into Kd[0]); S_c propagated by chunk scan over local end-states.

#define BATCH   2
#define SEQLEN  2048
#define DMODEL  512
#define DSTATE  64
#define T_CHUNK 64
#define NCHUNK  (SEQLEN / T_CHUNK)   // 32
#define RT      8                    // t' per thread in k_out
#define HP      2                    // h per thread in k_out (float2)

__device__ __forceinline__ float A_cont(int n) {
    // A[n] = (1 + (n+1)/64)^(-1/2)
    return rsqrtf(1.0f + (float)(n + 1) * (1.0f / 64.0f));
}

// ---------------- Kernel 1: fused setup + xlocal ----------------
// blocks 0..127   : setup  (Kbuf[72][512], AdTab[64][512], CpowStep[8][64][512])
// blocks 128..1151: xlocal (xl[b][c][n][h], lane = h, 8 states/lane)
__global__ __launch_bounds__(256) void k_prep(const float* __restrict__ u,
                                              const float* __restrict__ B_re,
                                              const float* __restrict__ C_re,
                                              const float* __restrict__ log_dt,
                                              const float* __restrict__ D,
                                              float* __restrict__ Kbuf,
                                              float* __restrict__ AdTab,
                                              float* __restrict__ CpowStep,
                                              float* __restrict__ xl) {
    if (blockIdx.x < 128) {
        int g = blockIdx.x * 256 + threadIdx.x;     // 32768 threads: (j, h)
        int h = g & (DMODEL - 1);
        int j = g >> 9;                             // 0..63
        float delta = expf(log_dt[h]);
        float dAj = delta * A_cont(j);
        float Adj = expf(dAj);
        AdTab[j * DMODEL + h] = Adj;
        float e8 = Adj * Adj; e8 = e8 * e8; e8 = e8 * e8;   // Adj^8
        float p = C_re[j] * Adj;                            // C*Ad^1
        #pragma unroll
        for (int i = 0; i < RT; ++i) {
            CpowStep[(i * DSTATE + j) * DMODEL + h] = p;
            p *= e8;
        }
        // K row tau=j: sum_n C[n]*Bd[n,h]*Ad[n,h]^j  (+D at j=0)
        float acc = (j == 0) ? D[h] : 0.0f;
        for (int n = 0; n < DSTATE; ++n) {
            float dAn = delta * A_cont(n);
            float Bd = expm1f(dAn) * B_re[n] * delta;
            acc = fmaf(C_re[n] * Bd, expf(dAn * (float)j), acc);
        }
        Kbuf[(8 + j) * DMODEL + h] = acc;
        if (j < 8) Kbuf[j * DMODEL + h] = 0.0f;     // zero-pad rows, branch-free conv
    } else {
        int g = (blockIdx.x - 128) * 256 + threadIdx.x;   // 262144 threads
        int lane = g & 63;
        int w = g >> 6;
        int hb = w & 7;              // h block (8 x 64)
        int ng = (w >> 3) & 7;       // n group (8 x 8)
        int c  = (w >> 6) & (NCHUNK - 1);
        int b  = w >> 11;
        int h = hb * 64 + lane;
        float delta = expf(log_dt[h]);
        float Ad[8], Bd[8], x[8];
        #pragma unroll
        for (int nn = 0; nn < 8; ++nn) {
            int n = ng * 8 + nn;
            float dA = delta * A_cont(n);
            Ad[nn] = expf(dA);
            Bd[nn] = expm1f(dA) * B_re[n] * delta;
            x[nn] = 0.0f;
        }
        const float* up = u + ((size_t)(b * SEQLEN + c * T_CHUNK)) * DMODEL + h;
        #pragma unroll 4
        for (int s = 0; s < T_CHUNK; ++s) {
            float uv = up[(size_t)s * DMODEL];      // coalesced in h
            #pragma unroll
            for (int nn = 0; nn < 8; ++nn)
                x[nn] = fmaf(Ad[nn], x[nn], Bd[nn] * uv);
        }
        float* xp = xl + ((size_t)((b * NCHUNK + c) * DSTATE + ng * 8)) * DMODEL + h;
        #pragma unroll
        for (int nn = 0; nn < 8; ++nn) xp[(size_t)nn * DMODEL] = x[nn];
    }
}

// ---------------- Kernel 2: chunk-state scan, fully unrolled ----------------
// Loads all 31 values (independent, in flight together), fma chain, stores all.
// After: xl[b][c-1][n][h] holds S_c (state entering chunk c), c = 1..NC-1.
__global__ __launch_bounds__(256) void k_scan(const float* __restrict__ log_dt,
                                              float* __restrict__ xl) {
    int g = blockIdx.x * 256 + threadIdx.x;   // 65536 threads, h fastest
    int h = g & (DMODEL - 1);
    int n = (g >> 9) & (DSTATE - 1);
    int b = g >> 15;
    float delta = expf(log_dt[h]);
    float ApT = expf(delta * A_cont(n) * (float)T_CHUNK);   // A_d^T
    float* base = xl + ((size_t)(b * NCHUNK * DSTATE + n)) * DMODEL + h;
    float v[NCHUNK - 1];
    #pragma unroll
    for (int c = 0; c < NCHUNK - 1; ++c)
        v[c] = base[(size_t)c * DSTATE * DMODEL];
    float s = 0.0f;
    #pragma unroll
    for (int c = 0; c < NCHUNK - 1; ++c) {
        s = fmaf(ApT, s, v[c]);
        v[c] = s;
    }
    #pragma unroll
    for (int c = 0; c < NCHUNK - 1; ++c)
        base[(size_t)c * DSTATE * DMODEL] = v[c];
}

// ---------------- Kernel 3: output, 8 t' x 2 h per thread ----------------
__global__ __launch_bounds__(256) void k_out(const float* __restrict__ u,
                                             const float* __restrict__ Kbuf,
                                             const float* __restrict__ AdTab,
                                             const float* __restrict__ CpowStep,
                                             const float* __restrict__ Sbuf,
                                             float* __restrict__ out) {
    int g = blockIdx.x * 256 + threadIdx.x;   // 131072 threads
    int h2 = g & 255;                 // h-pair index; h = 2*h2
    int it = (g >> 8) & 7;            // t'-tile (block-uniform)
    int c  = (g >> 11) & (NCHUNK - 1);
    int b  = g >> 16;
    int h = h2 * 2;
    int tp0 = it * RT;
    const int S2 = DMODEL / 2;        // float2 stride

    const float2* ub = (const float2*)(u + ((size_t)(b * SEQLEN + c * T_CHUNK)) * DMODEL + h);
    const float2* kb = (const float2*)(Kbuf + h);

    float2 acc[RT], kreg[RT];
    #pragma unroll
    for (int i = 0; i < RT; ++i) {
        acc[i] = make_float2(0.0f, 0.0f);
        kreg[i] = kb[(size_t)(8 + tp0 + i) * S2];
    }

    // causal conv: sliding K-window; per step 2 dwordx2 loads + 16 FMA
    for (int s8 = 0; s8 <= it; ++s8) {
        #pragma unroll
        for (int q = 0; q < 8; ++q) {
            int s = s8 * 8 + q;
            float2 uv = ub[(size_t)s * S2];
            #pragma unroll
            for (int i = 0; i < RT; ++i) {
                acc[i].x = fmaf(kreg[i].x, uv.x, acc[i].x);
                acc[i].y = fmaf(kreg[i].y, uv.y, acc[i].y);
            }
            #pragma unroll
            for (int i = RT - 1; i > 0; --i) kreg[i] = kreg[i - 1];
            kreg[0] = kb[(size_t)(8 + tp0 - s - 1) * S2];   // hits zero rows at the end
        }
    }

    // chunk-entry-state correction: z[i] = sum_n C*Ad^(tp0+i+1) * S[n]
    if (c > 0) {
        const float2* sp = (const float2*)(Sbuf + ((size_t)((b * NCHUNK + (c - 1)) * DSTATE)) * DMODEL + h);
        const float2* ap = (const float2*)(AdTab + h);
        const float2* cp = (const float2*)(CpowStep + (size_t)(it * DSTATE) * DMODEL + h);
        #pragma unroll 4
        for (int n = 0; n < DSTATE; ++n) {
            float2 Sv  = sp[(size_t)n * S2];
            float2 Adv = ap[(size_t)n * S2];
            float2 Cv  = cp[(size_t)n * S2];
            float2 w = make_float2(Cv.x * Sv.x, Cv.y * Sv.y);
            acc[0].x += w.x; acc[0].y += w.y;
            #pragma unroll
            for (int i = 1; i < RT; ++i) {
                w.x *= Adv.x; w.y *= Adv.y;
                acc[i].x += w.x; acc[i].y += w.y;
            }
        }
    }

    float2* ob = (float2*)(out + ((size_t)(b * SEQLEN + c * T_CHUNK + tp0)) * DMODEL + h);
    #pragma unroll
    for (int i = 0; i < RT; ++i) ob[(size_t)i * S2] = acc[i];
}

extern "C" void kernel_launch(void* const* d_in, const int* in_sizes, int n_in,
                              void* d_out, int out_size, void* d_ws, size_t ws_size,
                              hipStream_t stream) {
    const float* u      = (const float*)d_in[0];
    const float* B_re   = (const float*)d_in[1];
    const float* C_re   = (const float*)d_in[2];
    const float* log_dt = (const float*)d_in[3];
    const float* D      = (const float*)d_in[4];
    float* out = (float*)d_out;
    float* ws  = (float*)d_ws;

    // ws layout (floats):
    float* Kbuf     = ws;                           // 72*512   = 36864
    float* AdTab    = ws + 36864;                   // 64*512   = 32768
    float* CpowStep = ws + 36864 + 32768;           // 8*64*512 = 262144
    float* xl       = ws + 36864 + 32768 + 262144;  // 2*32*64*512 = 2097152

    k_prep<<<1152, 256, 0, stream>>>(u, B_re, C_re, log_dt, D, Kbuf, AdTab, CpowStep, xl);
    k_scan<<<256, 256, 0, stream>>>(log_dt, xl);
    k_out <<<512, 256, 0, stream>>>(u, Kbuf, AdTab, CpowStep, xl, out);
}